// Round 10
// baseline (346.794 us; speedup 1.0000x reference)
//
#include <hip/hip_runtime.h>
#include <math.h>

// Problem constants
#define BATCH 8
#define CH    256
#define HDIM  56
#define WDIM  56
#define HW    (HDIM*WDIM)          // 3136
#define MTOT  (BATCH*HW)           // 25088
#define GRP   8
#define GC    32
#define NP    9                    // K*K
#define NOFF  (GRP*NP*2)           // 144
#define NMSK  (GRP*NP)             // 72
#define NTOT  (NOFF+NMSK)          // 216
#define POSB  4                    // positions per sample block

typedef float f32x4 __attribute__((ext_vector_type(4)));
typedef short s16x8 __attribute__((ext_vector_type(8)));

// split a,b into packed bf16 hi (truncation) and bf16 lo (exact remainder, truncated)
__device__ inline void split2(float a, float b, unsigned int& hp, unsigned int& lp)
{
    const unsigned int ua = __float_as_uint(a), ub = __float_as_uint(b);
    hp = (ub & 0xffff0000u) | (ua >> 16);
    const float ha = __uint_as_float(ua & 0xffff0000u);
    const float hb = __uint_as_float(ub & 0xffff0000u);
    const unsigned int la = __float_as_uint(a - ha), lb = __float_as_uint(b - hb);
    lp = (lb & 0xffff0000u) | (la >> 16);
}

// ---------------------------------------------------------------------------
// Transpose + split x (NCHW) -> xt_hi/xt_lo [m][k] bf16. 64x64 LDS tiles.
// xt_* OVERLAYS the f buffer (exactly MTOT*CH*4 bytes); f is rewritten by
// dw_ln_gelu only after gemm_in_mfma has consumed xt.
// ---------------------------------------------------------------------------
__global__ __launch_bounds__(256)
void xt_split_kernel(const float* __restrict__ x,
                     unsigned short* __restrict__ hi,
                     unsigned short* __restrict__ lo)
{
    __shared__ float lds[64][68];
    const int hw0 = blockIdx.x * 64;       // 49 tiles (3136/64)
    const int k0  = blockIdx.y * 64;       // 4 tiles
    const int b   = blockIdx.z;            // 8
    const int t = threadIdx.x;
    #pragma unroll
    for (int p = 0; p < 4; ++p) {
        const int kr = (t >> 4) + p * 16;
        const int hc = (t & 15) * 4;
        *(float4*)&lds[kr][hc] =
            *(const float4*)(x + ((size_t)b * CH + k0 + kr) * HW + hw0 + hc);
    }
    __syncthreads();
    const int ml = t >> 2;             // m-row 0..63
    const int kc = (t & 3) * 16;       // k base 0,16,32,48
    unsigned int hbuf[8], lbuf[8];
    #pragma unroll
    for (int j = 0; j < 16; j += 2)
        split2(lds[kc + j][ml], lds[kc + j + 1][ml], hbuf[j >> 1], lbuf[j >> 1]);
    const size_t row = (size_t)(b * HW + hw0 + ml) * CH + k0 + kc;
    *(uint4*)&hi[row]     = *(uint4*)&hbuf[0];
    *(uint4*)&hi[row + 8] = *(uint4*)&hbuf[4];
    *(uint4*)&lo[row]     = *(uint4*)&lbuf[0];
    *(uint4*)&lo[row + 8] = *(uint4*)&lbuf[4];
}

// ---------------------------------------------------------------------------
// GEMM in via bf16 MFMA: v = x^T @ w_in + b_in (NHWC out). Barrier-free,
// no LDS. A-operand = w_in^T [n][k] bf16 (wt3); B-operand = xt [m][k] bf16.
// Epilogue: float4 NHWC stores (lane's 4 accum regs are 4 consecutive n).
// ---------------------------------------------------------------------------
__global__ __launch_bounds__(256)
void gemm_in_mfma(const unsigned short* __restrict__ xhi, // [m][k]
                  const unsigned short* __restrict__ xlo,
                  const unsigned short* __restrict__ whi, // [n][k]
                  const unsigned short* __restrict__ wlo,
                  const float* __restrict__ bias,
                  float* __restrict__ v)                  // [MTOT,256]
{
    const int m0 = blockIdx.x * 256;
    const int n0 = blockIdx.y * 64;
    const int t = threadIdx.x;
    const int lane = t & 63, wv = t >> 6;
    const int mblk = m0 + wv * 64;
    const int fm = lane & 15;
    const int q  = lane >> 4;

    f32x4 acc[4][4];              // [nt][mt]
    const f32x4 zero = {0.0f, 0.0f, 0.0f, 0.0f};
    #pragma unroll
    for (int i = 0; i < 4; ++i)
        #pragma unroll
        for (int j = 0; j < 4; ++j) acc[i][j] = zero;

    const unsigned short *xrh[4], *xrl[4], *wrh[4], *wrl[4];
    #pragma unroll
    for (int mt = 0; mt < 4; ++mt) {
        xrh[mt] = xhi + (size_t)(mblk + mt*16 + fm) * CH + q * 8;
        xrl[mt] = xlo + (size_t)(mblk + mt*16 + fm) * CH + q * 8;
    }
    #pragma unroll
    for (int nt = 0; nt < 4; ++nt) {
        wrh[nt] = whi + (size_t)(n0 + nt*16 + fm) * CH + q * 8;
        wrl[nt] = wlo + (size_t)(n0 + nt*16 + fm) * CH + q * 8;
    }

    for (int k0 = 0; k0 < CH; k0 += 32) {
        s16x8 wh[4], wl[4], ah[4], al[4];
        #pragma unroll
        for (int nt = 0; nt < 4; ++nt) {
            wh[nt] = *(const s16x8*)(wrh[nt] + k0);
            wl[nt] = *(const s16x8*)(wrl[nt] + k0);
        }
        #pragma unroll
        for (int mt = 0; mt < 4; ++mt) {
            ah[mt] = *(const s16x8*)(xrh[mt] + k0);
            al[mt] = *(const s16x8*)(xrl[mt] + k0);
        }
        #pragma unroll
        for (int nt = 0; nt < 4; ++nt)
            #pragma unroll
            for (int mt = 0; mt < 4; ++mt) {
                acc[nt][mt] = __builtin_amdgcn_mfma_f32_16x16x32_bf16(wh[nt], ah[mt], acc[nt][mt], 0, 0, 0);
                acc[nt][mt] = __builtin_amdgcn_mfma_f32_16x16x32_bf16(wh[nt], al[mt], acc[nt][mt], 0, 0, 0);
                acc[nt][mt] = __builtin_amdgcn_mfma_f32_16x16x32_bf16(wl[nt], ah[mt], acc[nt][mt], 0, 0, 0);
            }
    }

    // lane holds D[n = q*4+r][m = fm]; 4 regs = n..n+3 -> float4 NHWC store
    #pragma unroll
    for (int nt = 0; nt < 4; ++nt) {
        const float4 b4 = *(const float4*)&bias[n0 + nt*16 + q*4];
        #pragma unroll
        for (int mt = 0; mt < 4; ++mt) {
            f32x4 o = acc[nt][mt];
            o[0] += b4.x; o[1] += b4.y; o[2] += b4.z; o[3] += b4.w;
            *(f32x4*)&v[(size_t)(mblk + mt*16 + fm) * CH + n0 + nt*16 + q*4] = o;
        }
    }
}

// ---------------------------------------------------------------------------
// Fused depthwise 3x3 + bias + LayerNorm(C) + exact GELU -> f (NHWC)
// ---------------------------------------------------------------------------
__global__ __launch_bounds__(256)
void dw_ln_gelu_kernel(const float* __restrict__ x,
                       const float* __restrict__ dw_w,
                       const float* __restrict__ dw_b,
                       const float* __restrict__ ln_g,
                       const float* __restrict__ ln_b,
                       float* __restrict__ f)
{
    __shared__ float tile[WDIM][CH + 1];
    __shared__ float red1[WDIM][4], red2[WDIM][4];
    __shared__ float meanA[WDIM], rstdA[WDIM];

    const int h = blockIdx.x;
    const int b = blockIdx.y;
    const int t = threadIdx.x;
    const int lane = t & 63;
    const int wv   = t >> 6;

    for (int cg = 0; cg < CH / 4; ++cg) {
        const int c = cg * 4 + wv;
        const float* xp = x + ((size_t)b * CH + c) * HW;
        float rowv[3];
        #pragma unroll
        for (int r = 0; r < 3; ++r) {
            const int hh = h + r - 1;
            rowv[r] = (lane < WDIM && hh >= 0 && hh < HDIM) ? xp[hh * WDIM + lane] : 0.0f;
        }
        const float* wp = dw_w + c * 9;
        float acc = dw_b[c];
        #pragma unroll
        for (int r = 0; r < 3; ++r) {
            float L = __shfl_up(rowv[r], 1);
            float R = __shfl_down(rowv[r], 1);
            if (lane == 0) L = 0.0f;
            acc += L * wp[r * 3 + 0] + rowv[r] * wp[r * 3 + 1] + R * wp[r * 3 + 2];
        }
        if (lane < WDIM)
            tile[lane][c] = acc;
    }
    __syncthreads();

    if (t < 224) {
        const int p = t >> 2, q = t & 3;
        float s1 = 0.0f, s2 = 0.0f;
        #pragma unroll 8
        for (int i = 0; i < 64; ++i) {
            const float v = tile[p][q * 64 + i];
            s1 += v; s2 += v * v;
        }
        red1[p][q] = s1; red2[p][q] = s2;
    }
    __syncthreads();
    if (t < WDIM) {
        const float s1 = red1[t][0] + red1[t][1] + red1[t][2] + red1[t][3];
        const float s2 = red2[t][0] + red2[t][1] + red2[t][2] + red2[t][3];
        const float m = s1 * (1.0f / 256.0f);
        const float var = s2 * (1.0f / 256.0f) - m * m;
        meanA[t] = m;
        rstdA[t] = rsqrtf(var + 1e-5f);
    }
    __syncthreads();

    const float gam = ln_g[t], bet = ln_b[t];
    const size_t n0 = (size_t)(b * HDIM + h) * WDIM;
    for (int p = 0; p < WDIM; ++p) {
        const float xn = (tile[p][t] - meanA[p]) * rstdA[p] * gam + bet;
        const float g = 0.5f * xn * (1.0f + erff(xn * 0.70710678118654752f));
        f[(n0 + p) * CH + t] = g;
    }
}

// ---------------------------------------------------------------------------
// Transpose + hi/lo bf16 split of a [256k][256n] fp32 weight -> [n][k] bf16.
// ---------------------------------------------------------------------------
__global__ __launch_bounds__(256)
void wt_split_kernel(const float* __restrict__ w,
                     unsigned short* __restrict__ hi,
                     unsigned short* __restrict__ lo)
{
    __shared__ float lds[64][68];
    const int kt = blockIdx.x * 64, nt = blockIdx.y * 64;
    const int t = threadIdx.x;
    #pragma unroll
    for (int p = 0; p < 4; ++p) {
        const int kr = (t >> 4) + p * 16, nc = (t & 15) * 4;
        *(float4*)&lds[kr][nc] = *(const float4*)(w + (size_t)(kt + kr) * CH + nt + nc);
    }
    __syncthreads();
    const int nl = t >> 2, kc = (t & 3) * 16;
    #pragma unroll
    for (int j = 0; j < 16; j += 2) {
        const float f0 = lds[kc + j][nl], f1 = lds[kc + j + 1][nl];
        unsigned int hp, lp;
        split2(f0, f1, hp, lp);
        *(unsigned int*)&hi[(size_t)(nt + nl) * CH + kt + kc + j] = hp;
        *(unsigned int*)&lo[(size_t)(nt + nl) * CH + kt + kc + j] = lp;
    }
}

// ---------------------------------------------------------------------------
// Transpose + split of [w_off | w_mask] -> wt2_hi/lo [256 n_pad][256 k] bf16.
// ---------------------------------------------------------------------------
__global__ __launch_bounds__(256)
void wt2_split_kernel(const float* __restrict__ w_off,   // [256][144]
                      const float* __restrict__ w_mask,  // [256][72]
                      unsigned short* __restrict__ hi,
                      unsigned short* __restrict__ lo)
{
    const int n = threadIdx.x;
    const int k0 = blockIdx.x * 16;
    #pragma unroll
    for (int j = 0; j < 16; j += 2) {
        const int k = k0 + j;
        float f0 = 0.0f, f1 = 0.0f;
        if (n < NOFF) {
            f0 = w_off[(size_t)k * NOFF + n];
            f1 = w_off[(size_t)(k + 1) * NOFF + n];
        } else if (n < NTOT) {
            f0 = w_mask[(size_t)k * NMSK + (n - NOFF)];
            f1 = w_mask[(size_t)(k + 1) * NMSK + (n - NOFF)];
        }
        unsigned int hp, lp;
        split2(f0, f1, hp, lp);
        *(unsigned int*)&hi[(size_t)n * CH + k] = hp;
        *(unsigned int*)&lo[(size_t)n * CH + k] = lp;
    }
}

// ---------------------------------------------------------------------------
// Fused offset+mask GEMM via bf16 MFMA (validated structure).
// ---------------------------------------------------------------------------
__global__ __launch_bounds__(256)
void gemm_offmask_mfma(const float* __restrict__ A,            // f [MTOT,256]
                       const unsigned short* __restrict__ whi, // [256][256] bf16
                       const unsigned short* __restrict__ wlo,
                       const float* __restrict__ b_off,
                       const float* __restrict__ b_mask,
                       float* __restrict__ offb,               // [MTOT,144]
                       float* __restrict__ mskb)               // [MTOT,72]
{
    const int m0 = blockIdx.x * 256;
    const int n0 = blockIdx.y * 64;
    const int t = threadIdx.x;
    const int lane = t & 63, wv = t >> 6;
    const int mblk = m0 + wv * 64;
    const int fm = lane & 15;
    const int q  = lane >> 4;

    f32x4 acc[4][4];
    const f32x4 zero = {0.0f, 0.0f, 0.0f, 0.0f};
    #pragma unroll
    for (int i = 0; i < 4; ++i)
        #pragma unroll
        for (int j = 0; j < 4; ++j) acc[i][j] = zero;

    const float* arow[4];
    const unsigned short* wrh[4];
    const unsigned short* wrl[4];
    #pragma unroll
    for (int mt = 0; mt < 4; ++mt)
        arow[mt] = A + (size_t)(mblk + mt*16 + fm) * CH + q * 8;
    #pragma unroll
    for (int nt = 0; nt < 4; ++nt) {
        wrh[nt] = whi + (size_t)(n0 + nt*16 + fm) * CH + q * 8;
        wrl[nt] = wlo + (size_t)(n0 + nt*16 + fm) * CH + q * 8;
    }

    for (int k0 = 0; k0 < CH; k0 += 32) {
        s16x8 wh[4], wl[4], sh[4], sl[4];
        #pragma unroll
        for (int nt = 0; nt < 4; ++nt) {
            wh[nt] = *(const s16x8*)(wrh[nt] + k0);
            wl[nt] = *(const s16x8*)(wrl[nt] + k0);
        }
        #pragma unroll
        for (int mt = 0; mt < 4; ++mt) {
            const f32x4 r0 = *(const f32x4*)(arow[mt] + k0);
            const f32x4 r1 = *(const f32x4*)(arow[mt] + k0 + 4);
            union { s16x8 v; unsigned int u[4]; } ph, pl;
            split2(r0[0], r0[1], ph.u[0], pl.u[0]);
            split2(r0[2], r0[3], ph.u[1], pl.u[1]);
            split2(r1[0], r1[1], ph.u[2], pl.u[2]);
            split2(r1[2], r1[3], ph.u[3], pl.u[3]);
            sh[mt] = ph.v; sl[mt] = pl.v;
        }
        #pragma unroll
        for (int nt = 0; nt < 4; ++nt)
            #pragma unroll
            for (int mt = 0; mt < 4; ++mt) {
                acc[nt][mt] = __builtin_amdgcn_mfma_f32_16x16x32_bf16(wh[nt], sh[mt], acc[nt][mt], 0, 0, 0);
                acc[nt][mt] = __builtin_amdgcn_mfma_f32_16x16x32_bf16(wh[nt], sl[mt], acc[nt][mt], 0, 0, 0);
                acc[nt][mt] = __builtin_amdgcn_mfma_f32_16x16x32_bf16(wl[nt], sh[mt], acc[nt][mt], 0, 0, 0);
            }
    }

    #pragma unroll
    for (int nt = 0; nt < 4; ++nt) {
        #pragma unroll
        for (int r = 0; r < 4; ++r) {
            const int n = n0 + nt*16 + q*4 + r;
            if (n >= NTOT) continue;
            const float bs = (n < NOFF) ? b_off[n] : b_mask[n - NOFF];
            #pragma unroll
            for (int mt = 0; mt < 4; ++mt) {
                const int m = mblk + mt*16 + fm;
                const float val = acc[nt][mt][r] + bs;
                if (n < NOFF) offb[(size_t)m * NOFF + n] = val;
                else          mskb[(size_t)m * NMSK + (n - NOFF)] = val;
            }
        }
    }
}

// ---------------------------------------------------------------------------
// Deformable sampling (unchanged).
// ---------------------------------------------------------------------------
__global__ __launch_bounds__(256)
void sample_kernel(const float* __restrict__ v,
                   const float* __restrict__ offb,
                   const float* __restrict__ mskb,
                   float* __restrict__ s)
{
    __shared__ alignas(16) float loff[POSB][NOFF];
    __shared__ alignas(16) float lmsk[POSB][NMSK];
    __shared__ alignas(16) float wtab[POSB][GRP*NP][4];
    __shared__ alignas(16) int   itab[POSB][GRP*NP][4];

    const int n0 = blockIdx.x * POSB;
    const int t = threadIdx.x;

    if (t < POSB * (NOFF/4)) {
        const int q = t / (NOFF/4), r = t % (NOFF/4);
        *(float4*)&loff[q][r*4] = *(const float4*)&offb[(size_t)(n0+q)*NOFF + r*4];
    } else if (t < POSB * (NOFF/4) + POSB * (NMSK/4)) {
        const int u = t - POSB * (NOFF/4);
        const int q = u / (NMSK/4), r = u % (NMSK/4);
        *(float4*)&lmsk[q][r*4] = *(const float4*)&mskb[(size_t)(n0+q)*NMSK + r*4];
    }
    __syncthreads();

    if (t < POSB * GRP) {
        const int q = t >> 3, g = t & 7;
        float* mm = &lmsk[q][g * NP];
        float mx = -1e30f;
        #pragma unroll
        for (int p = 0; p < NP; ++p) mx = fmaxf(mx, mm[p]);
        float sum = 0.0f;
        #pragma unroll
        for (int p = 0; p < NP; ++p) { const float e = __expf(mm[p] - mx); mm[p] = e; sum += e; }
        const float inv = 1.0f / sum;
        #pragma unroll
        for (int p = 0; p < NP; ++p) mm[p] *= inv;
    }
    __syncthreads();

    for (int u = t; u < POSB * GRP * NP; u += 256) {
        const int q = u / (GRP*NP), j = u % (GRP*NP);
        const int g = j / NP, p = j % NP;
        const int n = n0 + q;
        const int hw = n % HW;
        const int h = hw / WDIM, w = hw % WDIM;
        const float ox = loff[q][g*18 + p*2 + 0];
        const float oy = loff[q][g*18 + p*2 + 1];
        const float m  = lmsk[q][g*NP + p];
        const float px = (float)(w + p/3) + ox;
        const float py = (float)(h + p%3) + oy;
        const float fx = floorf(px), fy = floorf(py);
        const float wx = px - fx, wy = py - fy;
        const int x0 = (int)fx, y0 = (int)fy;
        const int x1 = x0 + 1, y1 = y0 + 1;
        const float vx0 = (x0 >= 1 && x0 < 57) ? 1.0f : 0.0f;
        const float vx1 = (x1 >= 1 && x1 < 57) ? 1.0f : 0.0f;
        const float vy0 = (y0 >= 1 && y0 < 57) ? 1.0f : 0.0f;
        const float vy1 = (y1 >= 1 && y1 < 57) ? 1.0f : 0.0f;
        const int x0c = min(max(x0, 1), 56), x1c = min(max(x1, 1), 56);
        const int y0c = min(max(y0, 1), 56), y1c = min(max(y1, 1), 56);
        wtab[q][j][0] = m * (1.0f-wx) * (1.0f-wy) * vx0 * vy0;
        wtab[q][j][1] = m * wx        * (1.0f-wy) * vx1 * vy0;
        wtab[q][j][2] = m * (1.0f-wx) * wy        * vx0 * vy1;
        wtab[q][j][3] = m * wx        * wy        * vx1 * vy1;
        itab[q][j][0] = ((y0c-1)*WDIM + (x0c-1)) * CH;
        itab[q][j][1] = ((y0c-1)*WDIM + (x1c-1)) * CH;
        itab[q][j][2] = ((y1c-1)*WDIM + (x0c-1)) * CH;
        itab[q][j][3] = ((y1c-1)*WDIM + (x1c-1)) * CH;
    }
    __syncthreads();

    const int q = t >> 6, lane = t & 63;
    const int n = n0 + q;
    const int b = n / HW;
    const int g = lane >> 3;
    const float* vb = v + (size_t)b*HW*CH + lane*4;
    float4 acc = {0.0f, 0.0f, 0.0f, 0.0f};
    #pragma unroll
    for (int p = 0; p < NP; ++p) {
        const int j = g*NP + p;
        const float4 wv = *(const float4*)&wtab[q][j][0];
        const int4  iv = *(const int4*)&itab[q][j][0];
        const float4 c0 = *(const float4*)(vb + iv.x);
        const float4 c1 = *(const float4*)(vb + iv.y);
        const float4 c2 = *(const float4*)(vb + iv.z);
        const float4 c3 = *(const float4*)(vb + iv.w);
        acc.x += wv.x*c0.x + wv.y*c1.x + wv.z*c2.x + wv.w*c3.x;
        acc.y += wv.x*c0.y + wv.y*c1.y + wv.z*c2.y + wv.w*c3.y;
        acc.z += wv.x*c0.z + wv.y*c1.z + wv.z*c2.z + wv.w*c3.z;
        acc.w += wv.x*c0.w + wv.y*c1.w + wv.z*c2.w + wv.w*c3.w;
    }
    *(float4*)&s[(size_t)n*CH + lane*4] = acc;
}

// ---------------------------------------------------------------------------
// GEMM out via bf16 MFMA: y = SiLU(BN(s @ w_out + b_out)) NCHW.
// ---------------------------------------------------------------------------
__global__ __launch_bounds__(256)
void gemm_out_mfma(const float* __restrict__ A,            // s [MTOT,256]
                   const unsigned short* __restrict__ whi, // [256 n][256 k] bf16
                   const unsigned short* __restrict__ wlo,
                   const float* __restrict__ bias,
                   const float* __restrict__ bn_g,
                   const float* __restrict__ bn_b,
                   const float* __restrict__ bn_mean,
                   const float* __restrict__ bn_var,
                   float* __restrict__ y)                  // [B,256,3136]
{
    const int m0 = blockIdx.x * 256;
    const int n0 = blockIdx.y * 64;
    const int t = threadIdx.x;
    const int lane = t & 63, wv = t >> 6;
    const int mblk = m0 + wv * 64;
    const int fm = lane & 15;
    const int q  = lane >> 4;

    f32x4 acc[4][4];
    const f32x4 zero = {0.0f, 0.0f, 0.0f, 0.0f};
    #pragma unroll
    for (int i = 0; i < 4; ++i)
        #pragma unroll
        for (int j = 0; j < 4; ++j) acc[i][j] = zero;

    const float* arow[4];
    const unsigned short* wrh[4];
    const unsigned short* wrl[4];
    #pragma unroll
    for (int mt = 0; mt < 4; ++mt)
        arow[mt] = A + (size_t)(mblk + mt*16 + fm) * CH + q * 8;
    #pragma unroll
    for (int nt = 0; nt < 4; ++nt) {
        wrh[nt] = whi + (size_t)(n0 + nt*16 + fm) * CH + q * 8;
        wrl[nt] = wlo + (size_t)(n0 + nt*16 + fm) * CH + q * 8;
    }

    for (int k0 = 0; k0 < CH; k0 += 32) {
        s16x8 wh[4], wl[4], sh[4], sl[4];
        #pragma unroll
        for (int nt = 0; nt < 4; ++nt) {
            wh[nt] = *(const s16x8*)(wrh[nt] + k0);
            wl[nt] = *(const s16x8*)(wrl[nt] + k0);
        }
        #pragma unroll
        for (int mt = 0; mt < 4; ++mt) {
            const f32x4 r0 = *(const f32x4*)(arow[mt] + k0);
            const f32x4 r1 = *(const f32x4*)(arow[mt] + k0 + 4);
            union { s16x8 v; unsigned int u[4]; } ph, pl;
            split2(r0[0], r0[1], ph.u[0], pl.u[0]);
            split2(r0[2], r0[3], ph.u[1], pl.u[1]);
            split2(r1[0], r1[1], ph.u[2], pl.u[2]);
            split2(r1[2], r1[3], ph.u[3], pl.u[3]);
            sh[mt] = ph.v; sl[mt] = pl.v;
        }
        #pragma unroll
        for (int nt = 0; nt < 4; ++nt)
            #pragma unroll
            for (int mt = 0; mt < 4; ++mt) {
                acc[nt][mt] = __builtin_amdgcn_mfma_f32_16x16x32_bf16(wh[nt], sh[mt], acc[nt][mt], 0, 0, 0);
                acc[nt][mt] = __builtin_amdgcn_mfma_f32_16x16x32_bf16(wh[nt], sl[mt], acc[nt][mt], 0, 0, 0);
                acc[nt][mt] = __builtin_amdgcn_mfma_f32_16x16x32_bf16(wl[nt], sh[mt], acc[nt][mt], 0, 0, 0);
            }
    }

    #pragma unroll
    for (int nt = 0; nt < 4; ++nt) {
        #pragma unroll
        for (int r = 0; r < 4; ++r) {
            const int n = n0 + nt*16 + q*4 + r;
            const float sc = bn_g[n] * rsqrtf(bn_var[n] + 1e-5f);
            const float sb = bn_b[n] - bn_mean[n] * sc;
            const float bs = bias[n];
            #pragma unroll
            for (int mt = 0; mt < 4; ++mt) {
                const int mm = mblk + mt*16;
                const size_t base = (size_t)(mm / HW) * CH * HW + (mm % HW);
                float val = (acc[nt][mt][r] + bs) * sc + sb;
                y[base + (size_t)n * HW + fm] = val / (1.0f + expf(-val));
            }
        }
    }
}

extern "C" void kernel_launch(void* const* d_in, const int* in_sizes, int n_in,
                              void* d_out, int out_size, void* d_ws, size_t ws_size,
                              hipStream_t stream) {
    const float* x      = (const float*)d_in[0];
    const float* w_in   = (const float*)d_in[1];
    const float* b_in   = (const float*)d_in[2];
    const float* dw_w   = (const float*)d_in[3];
    const float* dw_b   = (const float*)d_in[4];
    const float* ln_g   = (const float*)d_in[5];
    const float* ln_b   = (const float*)d_in[6];
    const float* w_off  = (const float*)d_in[7];
    const float* b_off  = (const float*)d_in[8];
    const float* w_mask = (const float*)d_in[9];
    const float* b_mask = (const float*)d_in[10];
    const float* w_out  = (const float*)d_in[11];
    const float* b_out  = (const float*)d_in[12];
    const float* bn_g   = (const float*)d_in[13];
    const float* bn_b   = (const float*)d_in[14];
    const float* bn_mean= (const float*)d_in[15];
    const float* bn_var = (const float*)d_in[16];
    float* out = (float*)d_out;

    float* ws   = (float*)d_ws;
    float* v    = ws;                                   // MTOT*CH f32
    float* f    = v + (size_t)MTOT*CH;                  // MTOT*CH f32
    float* offb = f + (size_t)MTOT*CH;                  // MTOT*NOFF
    float* mskb = offb + (size_t)MTOT*NOFF;             // MTOT*NMSK
    float* s    = f;                                    // reuse f buffer
    unsigned short* wt_hi  = (unsigned short*)(mskb + (size_t)MTOT*NMSK);  // w_out^T
    unsigned short* wt_lo  = wt_hi + CH*CH;
    unsigned short* wt2_hi = wt_lo + CH*CH;                                // off|mask^T
    unsigned short* wt2_lo = wt2_hi + CH*CH;
    unsigned short* wt3_hi = wt2_lo + CH*CH;                               // w_in^T
    unsigned short* wt3_lo = wt3_hi + CH*CH;
    // xt overlays f: consumed by gemm_in_mfma BEFORE dw_ln_gelu rewrites f.
    unsigned short* xt_hi = (unsigned short*)f;
    unsigned short* xt_lo = xt_hi + (size_t)MTOT*CH;

    wt_split_kernel<<<dim3(4, 4), dim3(256), 0, stream>>>(w_out, wt_hi, wt_lo);
    wt_split_kernel<<<dim3(4, 4), dim3(256), 0, stream>>>(w_in, wt3_hi, wt3_lo);
    wt2_split_kernel<<<dim3(16), dim3(256), 0, stream>>>(w_off, w_mask, wt2_hi, wt2_lo);
    xt_split_kernel<<<dim3(HW/64, CH/64, BATCH), dim3(256), 0, stream>>>(x, xt_hi, xt_lo);
    gemm_in_mfma<<<dim3(MTOT/256, CH/64), dim3(256), 0, stream>>>(
        xt_hi, xt_lo, wt3_hi, wt3_lo, b_in, v);
    dw_ln_gelu_kernel<<<dim3(HDIM, BATCH), dim3(256), 0, stream>>>(x, dw_w, dw_b, ln_g, ln_b, f);
    gemm_offmask_mfma<<<dim3(MTOT/256, 4), dim3(256), 0, stream>>>(
        f, wt2_hi, wt2_lo, b_off, b_mask, offb, mskb);
    sample_kernel<<<dim3(MTOT/POSB), dim3(256), 0, stream>>>(v, offb, mskb, s);
    gemm_out_mfma<<<dim3(MTOT/256, CH/64), dim3(256), 0, stream>>>(
        s, wt_hi, wt_lo, b_out, bn_g, bn_b, bn_mean, bn_var, out);
}

// Round 11
// 328.697 us; speedup vs baseline: 1.0551x; 1.0551x over previous
//
#include <hip/hip_runtime.h>
#include <math.h>

// Problem constants
#define BATCH 8
#define CH    256
#define HDIM  56
#define WDIM  56
#define HW    (HDIM*WDIM)          // 3136
#define MTOT  (BATCH*HW)           // 25088
#define GRP   8
#define GC    32
#define NP    9                    // K*K
#define NOFF  (GRP*NP*2)           // 144
#define NMSK  (GRP*NP)             // 72
#define NTOT  (NOFF+NMSK)          // 216
#define POSB  4                    // positions per sample block

typedef float f32x4 __attribute__((ext_vector_type(4)));
typedef short s16x8 __attribute__((ext_vector_type(8)));

// split a,b into packed bf16 hi (truncation) and bf16 lo (exact remainder, truncated)
__device__ inline void split2(float a, float b, unsigned int& hp, unsigned int& lp)
{
    const unsigned int ua = __float_as_uint(a), ub = __float_as_uint(b);
    hp = (ub & 0xffff0000u) | (ua >> 16);
    const float ha = __uint_as_float(ua & 0xffff0000u);
    const float hb = __uint_as_float(ub & 0xffff0000u);
    const unsigned int la = __float_as_uint(a - ha), lb = __float_as_uint(b - hb);
    lp = (lb & 0xffff0000u) | (la >> 16);
}

// ---------------------------------------------------------------------------
// Transpose + split x (NCHW) -> xt_hi/xt_lo [m][k] bf16. 64x64 LDS tiles.
// xt_* OVERLAYS the f buffer; f is rewritten by dw_ln_gelu only after
// gemm_in_mfma has consumed xt.
// ---------------------------------------------------------------------------
__global__ __launch_bounds__(256)
void xt_split_kernel(const float* __restrict__ x,
                     unsigned short* __restrict__ hi,
                     unsigned short* __restrict__ lo)
{
    __shared__ float lds[64][68];
    const int hw0 = blockIdx.x * 64;       // 49 tiles (3136/64)
    const int k0  = blockIdx.y * 64;       // 4 tiles
    const int b   = blockIdx.z;            // 8
    const int t = threadIdx.x;
    #pragma unroll
    for (int p = 0; p < 4; ++p) {
        const int kr = (t >> 4) + p * 16;
        const int hc = (t & 15) * 4;
        *(float4*)&lds[kr][hc] =
            *(const float4*)(x + ((size_t)b * CH + k0 + kr) * HW + hw0 + hc);
    }
    __syncthreads();
    const int ml = t >> 2;             // m-row 0..63
    const int kc = (t & 3) * 16;       // k base 0,16,32,48
    unsigned int hbuf[8], lbuf[8];
    #pragma unroll
    for (int j = 0; j < 16; j += 2)
        split2(lds[kc + j][ml], lds[kc + j + 1][ml], hbuf[j >> 1], lbuf[j >> 1]);
    const size_t row = (size_t)(b * HW + hw0 + ml) * CH + k0 + kc;
    *(uint4*)&hi[row]     = *(uint4*)&hbuf[0];
    *(uint4*)&hi[row + 8] = *(uint4*)&hbuf[4];
    *(uint4*)&lo[row]     = *(uint4*)&lbuf[0];
    *(uint4*)&lo[row + 8] = *(uint4*)&lbuf[4];
}

// ---------------------------------------------------------------------------
// GEMM in via bf16 MFMA: v = x^T @ w_in + b_in (NHWC out). Barrier-free.
// ---------------------------------------------------------------------------
__global__ __launch_bounds__(256)
void gemm_in_mfma(const unsigned short* __restrict__ xhi, // [m][k]
                  const unsigned short* __restrict__ xlo,
                  const unsigned short* __restrict__ whi, // [n][k]
                  const unsigned short* __restrict__ wlo,
                  const float* __restrict__ bias,
                  float* __restrict__ v)                  // [MTOT,256]
{
    const int m0 = blockIdx.x * 256;
    const int n0 = blockIdx.y * 64;
    const int t = threadIdx.x;
    const int lane = t & 63, wv = t >> 6;
    const int mblk = m0 + wv * 64;
    const int fm = lane & 15;
    const int q  = lane >> 4;

    f32x4 acc[4][4];              // [nt][mt]
    const f32x4 zero = {0.0f, 0.0f, 0.0f, 0.0f};
    #pragma unroll
    for (int i = 0; i < 4; ++i)
        #pragma unroll
        for (int j = 0; j < 4; ++j) acc[i][j] = zero;

    const unsigned short *xrh[4], *xrl[4], *wrh[4], *wrl[4];
    #pragma unroll
    for (int mt = 0; mt < 4; ++mt) {
        xrh[mt] = xhi + (size_t)(mblk + mt*16 + fm) * CH + q * 8;
        xrl[mt] = xlo + (size_t)(mblk + mt*16 + fm) * CH + q * 8;
    }
    #pragma unroll
    for (int nt = 0; nt < 4; ++nt) {
        wrh[nt] = whi + (size_t)(n0 + nt*16 + fm) * CH + q * 8;
        wrl[nt] = wlo + (size_t)(n0 + nt*16 + fm) * CH + q * 8;
    }

    for (int k0 = 0; k0 < CH; k0 += 32) {
        s16x8 wh[4], wl[4], ah[4], al[4];
        #pragma unroll
        for (int nt = 0; nt < 4; ++nt) {
            wh[nt] = *(const s16x8*)(wrh[nt] + k0);
            wl[nt] = *(const s16x8*)(wrl[nt] + k0);
        }
        #pragma unroll
        for (int mt = 0; mt < 4; ++mt) {
            ah[mt] = *(const s16x8*)(xrh[mt] + k0);
            al[mt] = *(const s16x8*)(xrl[mt] + k0);
        }
        #pragma unroll
        for (int nt = 0; nt < 4; ++nt)
            #pragma unroll
            for (int mt = 0; mt < 4; ++mt) {
                acc[nt][mt] = __builtin_amdgcn_mfma_f32_16x16x32_bf16(wh[nt], ah[mt], acc[nt][mt], 0, 0, 0);
                acc[nt][mt] = __builtin_amdgcn_mfma_f32_16x16x32_bf16(wh[nt], al[mt], acc[nt][mt], 0, 0, 0);
                acc[nt][mt] = __builtin_amdgcn_mfma_f32_16x16x32_bf16(wl[nt], ah[mt], acc[nt][mt], 0, 0, 0);
            }
    }

    #pragma unroll
    for (int nt = 0; nt < 4; ++nt) {
        const float4 b4 = *(const float4*)&bias[n0 + nt*16 + q*4];
        #pragma unroll
        for (int mt = 0; mt < 4; ++mt) {
            f32x4 o = acc[nt][mt];
            o[0] += b4.x; o[1] += b4.y; o[2] += b4.z; o[3] += b4.w;
            *(f32x4*)&v[(size_t)(mblk + mt*16 + fm) * CH + n0 + nt*16 + q*4] = o;
        }
    }
}

// ---------------------------------------------------------------------------
// Fused depthwise 3x3 + bias + LayerNorm(C) + exact GELU -> f (NHWC)
// ---------------------------------------------------------------------------
__global__ __launch_bounds__(256)
void dw_ln_gelu_kernel(const float* __restrict__ x,
                       const float* __restrict__ dw_w,
                       const float* __restrict__ dw_b,
                       const float* __restrict__ ln_g,
                       const float* __restrict__ ln_b,
                       float* __restrict__ f)
{
    __shared__ float tile[WDIM][CH + 1];
    __shared__ float red1[WDIM][4], red2[WDIM][4];
    __shared__ float meanA[WDIM], rstdA[WDIM];

    const int h = blockIdx.x;
    const int b = blockIdx.y;
    const int t = threadIdx.x;
    const int lane = t & 63;
    const int wv   = t >> 6;

    for (int cg = 0; cg < CH / 4; ++cg) {
        const int c = cg * 4 + wv;
        const float* xp = x + ((size_t)b * CH + c) * HW;
        float rowv[3];
        #pragma unroll
        for (int r = 0; r < 3; ++r) {
            const int hh = h + r - 1;
            rowv[r] = (lane < WDIM && hh >= 0 && hh < HDIM) ? xp[hh * WDIM + lane] : 0.0f;
        }
        const float* wp = dw_w + c * 9;
        float acc = dw_b[c];
        #pragma unroll
        for (int r = 0; r < 3; ++r) {
            float L = __shfl_up(rowv[r], 1);
            float R = __shfl_down(rowv[r], 1);
            if (lane == 0) L = 0.0f;
            acc += L * wp[r * 3 + 0] + rowv[r] * wp[r * 3 + 1] + R * wp[r * 3 + 2];
        }
        if (lane < WDIM)
            tile[lane][c] = acc;
    }
    __syncthreads();

    if (t < 224) {
        const int p = t >> 2, q = t & 3;
        float s1 = 0.0f, s2 = 0.0f;
        #pragma unroll 8
        for (int i = 0; i < 64; ++i) {
            const float v = tile[p][q * 64 + i];
            s1 += v; s2 += v * v;
        }
        red1[p][q] = s1; red2[p][q] = s2;
    }
    __syncthreads();
    if (t < WDIM) {
        const float s1 = red1[t][0] + red1[t][1] + red1[t][2] + red1[t][3];
        const float s2 = red2[t][0] + red2[t][1] + red2[t][2] + red2[t][3];
        const float m = s1 * (1.0f / 256.0f);
        const float var = s2 * (1.0f / 256.0f) - m * m;
        meanA[t] = m;
        rstdA[t] = rsqrtf(var + 1e-5f);
    }
    __syncthreads();

    const float gam = ln_g[t], bet = ln_b[t];
    const size_t n0 = (size_t)(b * HDIM + h) * WDIM;
    for (int p = 0; p < WDIM; ++p) {
        const float xn = (tile[p][t] - meanA[p]) * rstdA[p] * gam + bet;
        const float g = 0.5f * xn * (1.0f + erff(xn * 0.70710678118654752f));
        f[(n0 + p) * CH + t] = g;
    }
}

// ---------------------------------------------------------------------------
// Transpose + hi/lo bf16 split of a [256k][256n] fp32 weight -> [n][k] bf16.
// ---------------------------------------------------------------------------
__global__ __launch_bounds__(256)
void wt_split_kernel(const float* __restrict__ w,
                     unsigned short* __restrict__ hi,
                     unsigned short* __restrict__ lo)
{
    __shared__ float lds[64][68];
    const int kt = blockIdx.x * 64, nt = blockIdx.y * 64;
    const int t = threadIdx.x;
    #pragma unroll
    for (int p = 0; p < 4; ++p) {
        const int kr = (t >> 4) + p * 16, nc = (t & 15) * 4;
        *(float4*)&lds[kr][nc] = *(const float4*)(w + (size_t)(kt + kr) * CH + nt + nc);
    }
    __syncthreads();
    const int nl = t >> 2, kc = (t & 3) * 16;
    #pragma unroll
    for (int j = 0; j < 16; j += 2) {
        const float f0 = lds[kc + j][nl], f1 = lds[kc + j + 1][nl];
        unsigned int hp, lp;
        split2(f0, f1, hp, lp);
        *(unsigned int*)&hi[(size_t)(nt + nl) * CH + kt + kc + j] = hp;
        *(unsigned int*)&lo[(size_t)(nt + nl) * CH + kt + kc + j] = lp;
    }
}

// ---------------------------------------------------------------------------
// Transpose + split of [w_off | w_mask] -> wt2_hi/lo [256 n_pad][256 k] bf16.
// ---------------------------------------------------------------------------
__global__ __launch_bounds__(256)
void wt2_split_kernel(const float* __restrict__ w_off,   // [256][144]
                      const float* __restrict__ w_mask,  // [256][72]
                      unsigned short* __restrict__ hi,
                      unsigned short* __restrict__ lo)
{
    const int n = threadIdx.x;
    const int k0 = blockIdx.x * 16;
    #pragma unroll
    for (int j = 0; j < 16; j += 2) {
        const int k = k0 + j;
        float f0 = 0.0f, f1 = 0.0f;
        if (n < NOFF) {
            f0 = w_off[(size_t)k * NOFF + n];
            f1 = w_off[(size_t)(k + 1) * NOFF + n];
        } else if (n < NTOT) {
            f0 = w_mask[(size_t)k * NMSK + (n - NOFF)];
            f1 = w_mask[(size_t)(k + 1) * NMSK + (n - NOFF)];
        }
        unsigned int hp, lp;
        split2(f0, f1, hp, lp);
        *(unsigned int*)&hi[(size_t)n * CH + k] = hp;
        *(unsigned int*)&lo[(size_t)n * CH + k] = lp;
    }
}

// ---------------------------------------------------------------------------
// Fused offset+mask GEMM via bf16 MFMA (validated structure).
// ---------------------------------------------------------------------------
__global__ __launch_bounds__(256)
void gemm_offmask_mfma(const float* __restrict__ A,            // f [MTOT,256]
                       const unsigned short* __restrict__ whi, // [256][256] bf16
                       const unsigned short* __restrict__ wlo,
                       const float* __restrict__ b_off,
                       const float* __restrict__ b_mask,
                       float* __restrict__ offb,               // [MTOT,144]
                       float* __restrict__ mskb)               // [MTOT,72]
{
    const int m0 = blockIdx.x * 256;
    const int n0 = blockIdx.y * 64;
    const int t = threadIdx.x;
    const int lane = t & 63, wv = t >> 6;
    const int mblk = m0 + wv * 64;
    const int fm = lane & 15;
    const int q  = lane >> 4;

    f32x4 acc[4][4];
    const f32x4 zero = {0.0f, 0.0f, 0.0f, 0.0f};
    #pragma unroll
    for (int i = 0; i < 4; ++i)
        #pragma unroll
        for (int j = 0; j < 4; ++j) acc[i][j] = zero;

    const float* arow[4];
    const unsigned short* wrh[4];
    const unsigned short* wrl[4];
    #pragma unroll
    for (int mt = 0; mt < 4; ++mt)
        arow[mt] = A + (size_t)(mblk + mt*16 + fm) * CH + q * 8;
    #pragma unroll
    for (int nt = 0; nt < 4; ++nt) {
        wrh[nt] = whi + (size_t)(n0 + nt*16 + fm) * CH + q * 8;
        wrl[nt] = wlo + (size_t)(n0 + nt*16 + fm) * CH + q * 8;
    }

    for (int k0 = 0; k0 < CH; k0 += 32) {
        s16x8 wh[4], wl[4], sh[4], sl[4];
        #pragma unroll
        for (int nt = 0; nt < 4; ++nt) {
            wh[nt] = *(const s16x8*)(wrh[nt] + k0);
            wl[nt] = *(const s16x8*)(wrl[nt] + k0);
        }
        #pragma unroll
        for (int mt = 0; mt < 4; ++mt) {
            const f32x4 r0 = *(const f32x4*)(arow[mt] + k0);
            const f32x4 r1 = *(const f32x4*)(arow[mt] + k0 + 4);
            union { s16x8 v; unsigned int u[4]; } ph, pl;
            split2(r0[0], r0[1], ph.u[0], pl.u[0]);
            split2(r0[2], r0[3], ph.u[1], pl.u[1]);
            split2(r1[0], r1[1], ph.u[2], pl.u[2]);
            split2(r1[2], r1[3], ph.u[3], pl.u[3]);
            sh[mt] = ph.v; sl[mt] = pl.v;
        }
        #pragma unroll
        for (int nt = 0; nt < 4; ++nt)
            #pragma unroll
            for (int mt = 0; mt < 4; ++mt) {
                acc[nt][mt] = __builtin_amdgcn_mfma_f32_16x16x32_bf16(wh[nt], sh[mt], acc[nt][mt], 0, 0, 0);
                acc[nt][mt] = __builtin_amdgcn_mfma_f32_16x16x32_bf16(wh[nt], sl[mt], acc[nt][mt], 0, 0, 0);
                acc[nt][mt] = __builtin_amdgcn_mfma_f32_16x16x32_bf16(wl[nt], sh[mt], acc[nt][mt], 0, 0, 0);
            }
    }

    #pragma unroll
    for (int nt = 0; nt < 4; ++nt) {
        #pragma unroll
        for (int r = 0; r < 4; ++r) {
            const int n = n0 + nt*16 + q*4 + r;
            if (n >= NTOT) continue;
            const float bs = (n < NOFF) ? b_off[n] : b_mask[n - NOFF];
            #pragma unroll
            for (int mt = 0; mt < 4; ++mt) {
                const int m = mblk + mt*16 + fm;
                const float val = acc[nt][mt][r] + bs;
                if (n < NOFF) offb[(size_t)m * NOFF + n] = val;
                else          mskb[(size_t)m * NMSK + (n - NOFF)] = val;
            }
        }
    }
}

// ---------------------------------------------------------------------------
// Deformable sampling. XCD-aware swizzle: blocks land on XCDs round-robin by
// blockIdx%8, so map bid -> (bid%8)*784 + bid/8. Each XCD then covers exactly
// one batch image (784 blocks x 4 pos = 3136 = HW); its v slice (3.2 MB) fits
// the 4 MB per-XCD L2 instead of all XCDs thrashing the full 25.7 MB array.
// ---------------------------------------------------------------------------
__global__ __launch_bounds__(256)
void sample_kernel(const float* __restrict__ v,
                   const float* __restrict__ offb,
                   const float* __restrict__ mskb,
                   float* __restrict__ s)
{
    __shared__ alignas(16) float loff[POSB][NOFF];
    __shared__ alignas(16) float lmsk[POSB][NMSK];
    __shared__ alignas(16) float wtab[POSB][GRP*NP][4];
    __shared__ alignas(16) int   itab[POSB][GRP*NP][4];

    const int nblk = MTOT / POSB;            // 6272
    const int per  = nblk / 8;               // 784
    const int bid  = blockIdx.x;
    const int sw   = (bid % 8) * per + (bid / 8);
    const int n0 = sw * POSB;
    const int t = threadIdx.x;

    if (t < POSB * (NOFF/4)) {
        const int q = t / (NOFF/4), r = t % (NOFF/4);
        *(float4*)&loff[q][r*4] = *(const float4*)&offb[(size_t)(n0+q)*NOFF + r*4];
    } else if (t < POSB * (NOFF/4) + POSB * (NMSK/4)) {
        const int u = t - POSB * (NOFF/4);
        const int q = u / (NMSK/4), r = u % (NMSK/4);
        *(float4*)&lmsk[q][r*4] = *(const float4*)&mskb[(size_t)(n0+q)*NMSK + r*4];
    }
    __syncthreads();

    if (t < POSB * GRP) {
        const int q = t >> 3, g = t & 7;
        float* mm = &lmsk[q][g * NP];
        float mx = -1e30f;
        #pragma unroll
        for (int p = 0; p < NP; ++p) mx = fmaxf(mx, mm[p]);
        float sum = 0.0f;
        #pragma unroll
        for (int p = 0; p < NP; ++p) { const float e = __expf(mm[p] - mx); mm[p] = e; sum += e; }
        const float inv = 1.0f / sum;
        #pragma unroll
        for (int p = 0; p < NP; ++p) mm[p] *= inv;
    }
    __syncthreads();

    for (int u = t; u < POSB * GRP * NP; u += 256) {
        const int q = u / (GRP*NP), j = u % (GRP*NP);
        const int g = j / NP, p = j % NP;
        const int n = n0 + q;
        const int hw = n % HW;
        const int h = hw / WDIM, w = hw % WDIM;
        const float ox = loff[q][g*18 + p*2 + 0];
        const float oy = loff[q][g*18 + p*2 + 1];
        const float m  = lmsk[q][g*NP + p];
        const float px = (float)(w + p/3) + ox;
        const float py = (float)(h + p%3) + oy;
        const float fx = floorf(px), fy = floorf(py);
        const float wx = px - fx, wy = py - fy;
        const int x0 = (int)fx, y0 = (int)fy;
        const int x1 = x0 + 1, y1 = y0 + 1;
        const float vx0 = (x0 >= 1 && x0 < 57) ? 1.0f : 0.0f;
        const float vx1 = (x1 >= 1 && x1 < 57) ? 1.0f : 0.0f;
        const float vy0 = (y0 >= 1 && y0 < 57) ? 1.0f : 0.0f;
        const float vy1 = (y1 >= 1 && y1 < 57) ? 1.0f : 0.0f;
        const int x0c = min(max(x0, 1), 56), x1c = min(max(x1, 1), 56);
        const int y0c = min(max(y0, 1), 56), y1c = min(max(y1, 1), 56);
        wtab[q][j][0] = m * (1.0f-wx) * (1.0f-wy) * vx0 * vy0;
        wtab[q][j][1] = m * wx        * (1.0f-wy) * vx1 * vy0;
        wtab[q][j][2] = m * (1.0f-wx) * wy        * vx0 * vy1;
        wtab[q][j][3] = m * wx        * wy        * vx1 * vy1;
        itab[q][j][0] = ((y0c-1)*WDIM + (x0c-1)) * CH;
        itab[q][j][1] = ((y0c-1)*WDIM + (x1c-1)) * CH;
        itab[q][j][2] = ((y1c-1)*WDIM + (x0c-1)) * CH;
        itab[q][j][3] = ((y1c-1)*WDIM + (x1c-1)) * CH;
    }
    __syncthreads();

    const int q = t >> 6, lane = t & 63;
    const int n = n0 + q;
    const int b = n / HW;
    const int g = lane >> 3;
    const float* vb = v + (size_t)b*HW*CH + lane*4;
    float4 acc = {0.0f, 0.0f, 0.0f, 0.0f};
    #pragma unroll
    for (int p = 0; p < NP; ++p) {
        const int j = g*NP + p;
        const float4 wv = *(const float4*)&wtab[q][j][0];
        const int4  iv = *(const int4*)&itab[q][j][0];
        const float4 c0 = *(const float4*)(vb + iv.x);
        const float4 c1 = *(const float4*)(vb + iv.y);
        const float4 c2 = *(const float4*)(vb + iv.z);
        const float4 c3 = *(const float4*)(vb + iv.w);
        acc.x += wv.x*c0.x + wv.y*c1.x + wv.z*c2.x + wv.w*c3.x;
        acc.y += wv.x*c0.y + wv.y*c1.y + wv.z*c2.y + wv.w*c3.y;
        acc.z += wv.x*c0.z + wv.y*c1.z + wv.z*c2.z + wv.w*c3.z;
        acc.w += wv.x*c0.w + wv.y*c1.w + wv.z*c2.w + wv.w*c3.w;
    }
    *(float4*)&s[(size_t)n*CH + lane*4] = acc;
}

// ---------------------------------------------------------------------------
// GEMM out via bf16 MFMA: y = SiLU(BN(s @ w_out + b_out)) NCHW.
// ---------------------------------------------------------------------------
__global__ __launch_bounds__(256)
void gemm_out_mfma(const float* __restrict__ A,            // s [MTOT,256]
                   const unsigned short* __restrict__ whi, // [256 n][256 k] bf16
                   const unsigned short* __restrict__ wlo,
                   const float* __restrict__ bias,
                   const float* __restrict__ bn_g,
                   const float* __restrict__ bn_b,
                   const float* __restrict__ bn_mean,
                   const float* __restrict__ bn_var,
                   float* __restrict__ y)                  // [B,256,3136]
{
    const int m0 = blockIdx.x * 256;
    const int n0 = blockIdx.y * 64;
    const int t = threadIdx.x;
    const int lane = t & 63, wv = t >> 6;
    const int mblk = m0 + wv * 64;
    const int fm = lane & 15;
    const int q  = lane >> 4;

    f32x4 acc[4][4];
    const f32x4 zero = {0.0f, 0.0f, 0.0f, 0.0f};
    #pragma unroll
    for (int i = 0; i < 4; ++i)
        #pragma unroll
        for (int j = 0; j < 4; ++j) acc[i][j] = zero;

    const float* arow[4];
    const unsigned short* wrh[4];
    const unsigned short* wrl[4];
    #pragma unroll
    for (int mt = 0; mt < 4; ++mt)
        arow[mt] = A + (size_t)(mblk + mt*16 + fm) * CH + q * 8;
    #pragma unroll
    for (int nt = 0; nt < 4; ++nt) {
        wrh[nt] = whi + (size_t)(n0 + nt*16 + fm) * CH + q * 8;
        wrl[nt] = wlo + (size_t)(n0 + nt*16 + fm) * CH + q * 8;
    }

    for (int k0 = 0; k0 < CH; k0 += 32) {
        s16x8 wh[4], wl[4], sh[4], sl[4];
        #pragma unroll
        for (int nt = 0; nt < 4; ++nt) {
            wh[nt] = *(const s16x8*)(wrh[nt] + k0);
            wl[nt] = *(const s16x8*)(wrl[nt] + k0);
        }
        #pragma unroll
        for (int mt = 0; mt < 4; ++mt) {
            const f32x4 r0 = *(const f32x4*)(arow[mt] + k0);
            const f32x4 r1 = *(const f32x4*)(arow[mt] + k0 + 4);
            union { s16x8 v; unsigned int u[4]; } ph, pl;
            split2(r0[0], r0[1], ph.u[0], pl.u[0]);
            split2(r0[2], r0[3], ph.u[1], pl.u[1]);
            split2(r1[0], r1[1], ph.u[2], pl.u[2]);
            split2(r1[2], r1[3], ph.u[3], pl.u[3]);
            sh[mt] = ph.v; sl[mt] = pl.v;
        }
        #pragma unroll
        for (int nt = 0; nt < 4; ++nt)
            #pragma unroll
            for (int mt = 0; mt < 4; ++mt) {
                acc[nt][mt] = __builtin_amdgcn_mfma_f32_16x16x32_bf16(wh[nt], sh[mt], acc[nt][mt], 0, 0, 0);
                acc[nt][mt] = __builtin_amdgcn_mfma_f32_16x16x32_bf16(wh[nt], sl[mt], acc[nt][mt], 0, 0, 0);
                acc[nt][mt] = __builtin_amdgcn_mfma_f32_16x16x32_bf16(wl[nt], sh[mt], acc[nt][mt], 0, 0, 0);
            }
    }

    #pragma unroll
    for (int nt = 0; nt < 4; ++nt) {
        #pragma unroll
        for (int r = 0; r < 4; ++r) {
            const int n = n0 + nt*16 + q*4 + r;
            const float sc = bn_g[n] * rsqrtf(bn_var[n] + 1e-5f);
            const float sb = bn_b[n] - bn_mean[n] * sc;
            const float bs = bias[n];
            #pragma unroll
            for (int mt = 0; mt < 4; ++mt) {
                const int mm = mblk + mt*16;
                const size_t base = (size_t)(mm / HW) * CH * HW + (mm % HW);
                float val = (acc[nt][mt][r] + bs) * sc + sb;
                y[base + (size_t)n * HW + fm] = val / (1.0f + expf(-val));
            }
        }
    }
}

extern "C" void kernel_launch(void* const* d_in, const int* in_sizes, int n_in,
                              void* d_out, int out_size, void* d_ws, size_t ws_size,
                              hipStream_t stream) {
    const float* x      = (const float*)d_in[0];
    const float* w_in   = (const float*)d_in[1];
    const float* b_in   = (const float*)d_in[2];
    const float* dw_w   = (const float*)d_in[3];
    const float* dw_b   = (const float*)d_in[4];
    const float* ln_g   = (const float*)d_in[5];
    const float* ln_b   = (const float*)d_in[6];
    const float* w_off  = (const float*)d_in[7];
    const float* b_off  = (const float*)d_in[8];
    const float* w_mask = (const float*)d_in[9];
    const float* b_mask = (const float*)d_in[10];
    const float* w_out  = (const float*)d_in[11];
    const float* b_out  = (const float*)d_in[12];
    const float* bn_g   = (const float*)d_in[13];
    const float* bn_b   = (const float*)d_in[14];
    const float* bn_mean= (const float*)d_in[15];
    const float* bn_var = (const float*)d_in[16];
    float* out = (float*)d_out;

    float* ws   = (float*)d_ws;
    float* v    = ws;                                   // MTOT*CH f32
    float* f    = v + (size_t)MTOT*CH;                  // MTOT*CH f32
    float* offb = f + (size_t)MTOT*CH;                  // MTOT*NOFF
    float* mskb = offb + (size_t)MTOT*NOFF;             // MTOT*NMSK
    float* s    = f;                                    // reuse f buffer
    unsigned short* wt_hi  = (unsigned short*)(mskb + (size_t)MTOT*NMSK);  // w_out^T
    unsigned short* wt_lo  = wt_hi + CH*CH;
    unsigned short* wt2_hi = wt_lo + CH*CH;                                // off|mask^T
    unsigned short* wt2_lo = wt2_hi + CH*CH;
    unsigned short* wt3_hi = wt2_lo + CH*CH;                               // w_in^T
    unsigned short* wt3_lo = wt3_hi + CH*CH;
    // xt overlays f: consumed by gemm_in_mfma BEFORE dw_ln_gelu rewrites f.
    unsigned short* xt_hi = (unsigned short*)f;
    unsigned short* xt_lo = xt_hi + (size_t)MTOT*CH;

    wt_split_kernel<<<dim3(4, 4), dim3(256), 0, stream>>>(w_out, wt_hi, wt_lo);
    wt_split_kernel<<<dim3(4, 4), dim3(256), 0, stream>>>(w_in, wt3_hi, wt3_lo);
    wt2_split_kernel<<<dim3(16), dim3(256), 0, stream>>>(w_off, w_mask, wt2_hi, wt2_lo);
    xt_split_kernel<<<dim3(HW/64, CH/64, BATCH), dim3(256), 0, stream>>>(x, xt_hi, xt_lo);
    gemm_in_mfma<<<dim3(MTOT/256, CH/64), dim3(256), 0, stream>>>(
        xt_hi, xt_lo, wt3_hi, wt3_lo, b_in, v);
    dw_ln_gelu_kernel<<<dim3(HDIM, BATCH), dim3(256), 0, stream>>>(x, dw_w, dw_b, ln_g, ln_b, f);
    gemm_offmask_mfma<<<dim3(MTOT/256, 4), dim3(256), 0, stream>>>(
        f, wt2_hi, wt2_lo, b_off, b_mask, offb, mskb);
    sample_kernel<<<dim3(MTOT/POSB), dim3(256), 0, stream>>>(v, offb, mskb, s);
    gemm_out_mfma<<<dim3(MTOT/256, CH/64), dim3(256), 0, stream>>>(
        s, wt_hi, wt_lo, b_out, bn_g, bn_b, bn_mean, bn_var, out);
}